// Round 8
// baseline (1250.958 us; speedup 1.0000x reference)
//
#include <hip/hip_runtime.h>
#include <hip/hip_bf16.h>

typedef __attribute__((ext_vector_type(8))) short bf16x8_t;
typedef __attribute__((ext_vector_type(4))) float f32x4_t;

#define LD8(p) (*(const bf16x8_t*)(p))

// ---------------- f32 -> bf16 convert ----------------
__global__ __launch_bounds__(256) void k_cvt(const float* __restrict__ in,
                                             __hip_bfloat16* __restrict__ out, int n) {
  int i = blockIdx.x * 256 + threadIdx.x;
  if (i < n) out[i] = __float2bfloat16(in[i]);
}

// ---------------- cmbp: rpb+mask packed in MFMA C-fragment order ----------------
__global__ __launch_bounds__(256) void k_cmb(const int* __restrict__ rpi,
                                             const float* __restrict__ tab,
                                             const float* __restrict__ mask,
                                             float* __restrict__ cmbp) {
  int idx = blockIdx.x * 256 + threadIdx.x;   // < 64*16*16*256 = 4194304
  int jj = idx & 3, lane = (idx >> 2) & 63, tile = (idx >> 8) & 15;
  int h = (idx >> 12) & 15, w6 = idx >> 16;
  int r = (tile >> 2) * 16 + (lane >> 4) * 4 + jj;
  int c = (tile & 3) * 16 + (lane & 15);
  float v = -1e9f;
  if (r < 49 && c < 49) v = tab[rpi[r * 49 + c] * 16 + h] + mask[w6 * 2401 + r * 49 + c];
  cmbp[idx] = v;
}

// ---------------- layernorm (+optional shift+window-partition), f32 -> bf16 ----------------
template<int PERM>
__global__ __launch_bounds__(256) void k_ln(const float* __restrict__ in,
                                            const float* __restrict__ g,
                                            const float* __restrict__ bta,
                                            __hip_bfloat16* __restrict__ out) {
  int token = blockIdx.x;
  int t = threadIdx.x;
  const float2 v = ((const float2*)(in + (size_t)token * 512))[t];
  float s = v.x + v.y, sq = v.x * v.x + v.y * v.y;
  #pragma unroll
  for (int d = 1; d < 64; d <<= 1) { s += __shfl_xor(s, d); sq += __shfl_xor(sq, d); }
  __shared__ float ps[4], pq[4];
  int w = t >> 6;
  if ((t & 63) == 0) { ps[w] = s; pq[w] = sq; }
  __syncthreads();
  s  = ps[0] + ps[1] + ps[2] + ps[3];
  sq = pq[0] + pq[1] + pq[2] + pq[3];
  float mean = s * (1.f / 512.f);
  float inv = rsqrtf(sq * (1.f / 512.f) - mean * mean + 1e-5f);
  size_t dst;
  if (PERM) {
    int b = token / 3136, p = token - b * 3136;
    int i = p / 56, j = p - i * 56;
    int gi = (i + 53) % 56, gj = (j + 53) % 56;       // (i-3) mod 56
    dst = ((size_t)(((b * 64) + (gi / 7) * 8 + (gj / 7)) * 49) + (gi % 7) * 7 + (gj % 7)) * 512;
  } else {
    dst = (size_t)token * 512;
  }
  int c = t * 2;
  out[dst + c]     = __float2bfloat16((v.x - mean) * inv * g[c] + bta[c]);
  out[dst + c + 1] = __float2bfloat16((v.y - mean) * inv * g[c + 1] + bta[c + 1]);
}

// ---------------- MFMA windowed attention: one wave per (window, head) ----------------
__global__ __launch_bounds__(256) void k_attn(const __hip_bfloat16* __restrict__ qkv,
                                              const float* __restrict__ cmbp,
                                              __hip_bfloat16* __restrict__ o) {
  __shared__ __align__(16) __hip_bfloat16 vt_all[4 * 32 * 72];
  __shared__ __align__(16) __hip_bfloat16 P_all[4 * 64 * 72];
  const int t = threadIdx.x, l = t & 63, w = t >> 6;
  const int bw = blockIdx.x;
  const int head = blockIdx.y * 4 + w;
  const int rr = l & 15, g = l >> 4;
  __hip_bfloat16* vt = vt_all + w * (32 * 72);
  __hip_bfloat16* P  = P_all  + w * (64 * 72);
  const __hip_bfloat16* base = qkv + (size_t)bw * 49 * 1536 + head * 32;
  const bf16x8_t zero8 = {};

  { int d = l >> 1, sg = (l & 1) * 8;
    *(bf16x8_t*)(vt + d * 72 + 48 + sg) = zero8; }
  __builtin_amdgcn_sched_barrier(0);
  #pragma unroll
  for (int it = 0; it < 4; ++it) {
    int idx = l + it * 64;
    if (idx < 196) {
      int j = idx >> 2, sg = (idx & 3) * 8;
      bf16x8_t vv = *(const bf16x8_t*)(base + 1024 + (size_t)j * 1536 + sg);
      #pragma unroll
      for (int s2 = 0; s2 < 8; ++s2) vt[(sg + s2) * 72 + j] = ((__hip_bfloat16*)&vv)[s2];
    }
  }
  bf16x8_t aq[4], bk[4];
  #pragma unroll
  for (int m = 0; m < 4; ++m) {
    int row = m * 16 + rr;
    aq[m] = (row < 49) ? *(const bf16x8_t*)(base + (size_t)row * 1536 + g * 8) : zero8;
    bk[m] = (row < 49) ? *(const bf16x8_t*)(base + 512 + (size_t)row * 1536 + g * 8) : zero8;
  }
  const float4* cp = (const float4*)(cmbp + (size_t)((bw & 63) * 16 + head) * 4096);
  f32x4_t S[4][4];
  #pragma unroll
  for (int tm = 0; tm < 4; ++tm)
    #pragma unroll
    for (int tn = 0; tn < 4; ++tn) {
      float4 cv = cp[(tm * 4 + tn) * 64 + l];
      f32x4_t c0 = { cv.x, cv.y, cv.z, cv.w };
      S[tm][tn] = __builtin_amdgcn_mfma_f32_16x16x32_bf16(aq[tm], bk[tn], c0, 0, 0, 0);
    }
  float sm[4][4];
  #pragma unroll
  for (int tm = 0; tm < 4; ++tm) {
    #pragma unroll
    for (int jj = 0; jj < 4; ++jj) {
      float v = fmaxf(fmaxf(S[tm][0][jj], S[tm][1][jj]), fmaxf(S[tm][2][jj], S[tm][3][jj]));
      v = fmaxf(v, __shfl_xor(v, 1));
      v = fmaxf(v, __shfl_xor(v, 2));
      v = fmaxf(v, __shfl_xor(v, 4));
      v = fmaxf(v, __shfl_xor(v, 8));
      float s = 0.f;
      #pragma unroll
      for (int tn = 0; tn < 4; ++tn) {
        float e = __expf(S[tm][tn][jj] - v);
        S[tm][tn][jj] = e;
        s += e;
      }
      s += __shfl_xor(s, 1); s += __shfl_xor(s, 2); s += __shfl_xor(s, 4); s += __shfl_xor(s, 8);
      sm[tm][jj] = s;
    }
  }
  #pragma unroll
  for (int tm = 0; tm < 4; ++tm)
    #pragma unroll
    for (int tn = 0; tn < 4; ++tn)
      #pragma unroll
      for (int jj = 0; jj < 4; ++jj)
        P[(tm * 16 + g * 4 + jj) * 72 + tn * 16 + rr] = __float2bfloat16(S[tm][tn][jj]);

  f32x4_t O[4][2] = {};
  #pragma unroll
  for (int ks = 0; ks < 2; ++ks) {
    bf16x8_t pa[4], vb[2];
    #pragma unroll
    for (int tm = 0; tm < 4; ++tm)
      pa[tm] = *(const bf16x8_t*)(P + (tm * 16 + rr) * 72 + ks * 32 + g * 8);
    #pragma unroll
    for (int tn = 0; tn < 2; ++tn)
      vb[tn] = *(const bf16x8_t*)(vt + (tn * 16 + rr) * 72 + ks * 32 + g * 8);
    #pragma unroll
    for (int tm = 0; tm < 4; ++tm)
      #pragma unroll
      for (int tn = 0; tn < 2; ++tn)
        O[tm][tn] = __builtin_amdgcn_mfma_f32_16x16x32_bf16(pa[tm], vb[tn], O[tm][tn], 0, 0, 0);
  }
  #pragma unroll
  for (int tm = 0; tm < 4; ++tm) {
    #pragma unroll
    for (int jj = 0; jj < 4; ++jj) {
      int r = tm * 16 + g * 4 + jj;
      if (r < 49) {
        float rcp = 1.f / sm[tm][jj];
        size_t ob = ((size_t)bw * 49 + r) * 512 + head * 32;
        o[ob + rr]      = __float2bfloat16(O[tm][0][jj] * rcp);
        o[ob + 16 + rr] = __float2bfloat16(O[tm][1][jj] * rcp);
      }
    }
  }
}

// ---------------- 256x128 bf16 GEMM: B direct-from-global, A via ring-3 LDS ----------------
// 8 waves (4m x 2n), wave-tile 64x64, BK=32. Per tile: prefetch next-tile frags (ds_read A +
// global B, no dep on current MFMAs -> overlap), stage A via reg (dual S-sets, 2-body slack),
// one lgkmcnt(0)+s_barrier per tile. B weights are L1/L2-hot (<=2MB). T1 XCD swizzle, T5 setprio.
template<int EP>
__global__ __launch_bounds__(512, 1) void gemm_bd(const __hip_bfloat16* __restrict__ A,
                                                  const __hip_bfloat16* __restrict__ Bw,
                                                  int K, int Ncols, int nNB,
                                                  const float* __restrict__ bias,
                                                  __hip_bfloat16* __restrict__ obf,
                                                  const float* __restrict__ resid,
                                                  float* __restrict__ ofp) {
  __shared__ __align__(16) char LDS[49152];   // A ring-3 x 16KB
  const int nwg = gridDim.x, orig = blockIdx.x;
  const int q8 = nwg >> 3, r8 = nwg & 7;
  const int xcd = orig & 7, lin = orig >> 3;
  const int wgid = (xcd < r8 ? xcd * (q8 + 1) : r8 * (q8 + 1) + (xcd - r8) * q8) + lin;
  const int bx = wgid / nNB, by = wgid - bx * nNB;
  const int m0 = bx * 256, n0 = by * 128;
  const int t = threadIdx.x, l = t & 63, w = t >> 6;
  const int wr = w >> 1, wc = w & 1;
  const int rr = l & 15, kq = l >> 4;
  const int lofs = rr * 64 + ((kq * 16) ^ ((rr & 8) << 2));

  // A staging: linear source, swizzled LDS write (involution matches lofs)
  int rs0, cs0, rs1, cs1;
  { int d = t * 16;        rs0 = (d >> 10) * 16 + ((d >> 6) & 15); cs0 = (d & 63) >> 1; }
  { int d = 8192 + t * 16; rs1 = (d >> 10) * 16 + ((d >> 6) & 15); cs1 = (d & 63) >> 1; }
  const __hip_bfloat16* gA0 = A + (size_t)(m0 + rs0) * K + cs0;
  const __hip_bfloat16* gA1 = A + (size_t)(m0 + rs1) * K + cs1;
  const int d0i = t * 16, d1i = 8192 + t * 16;
  const int wz0 = (d0i & ~63) | ((d0i & 63) ^ (((d0i >> 9) & 1) << 5));
  const int wz1 = (d1i & ~63) | ((d1i & 63) ^ (((d1i >> 9) & 1) << 5));

  // B fragment base (direct global): row = n0 + wc*64 + n*16 + rr, byte seg kq*8
  const __hip_bfloat16* gB = Bw + (size_t)(n0 + wc * 64 + rr) * K + kq * 8;
  const size_t nstep = (size_t)16 * K;

  bf16x8_t sE0, sE1, sO0, sO1;   // dual staging sets (even/odd tiles)
  auto loadE  = [&](int tile) { int c = tile * 32; sE0 = LD8(gA0 + c); sE1 = LD8(gA1 + c); };
  auto loadO  = [&](int tile) { int c = tile * 32; sO0 = LD8(gA0 + c); sO1 = LD8(gA1 + c); };
  auto writeE = [&](int tile) { char* d = LDS + (tile % 3) * 16384;
                                *(bf16x8_t*)(d + wz0) = sE0; *(bf16x8_t*)(d + wz1) = sE1; };
  auto writeO = [&](int tile) { char* d = LDS + (tile % 3) * 16384;
                                *(bf16x8_t*)(d + wz0) = sO0; *(bf16x8_t*)(d + wz1) = sO1; };
  auto rdA = [&](bf16x8_t (&a)[4], int tile) {
    const char* b = LDS + (tile % 3) * 16384 + wr * 4096;
    #pragma unroll
    for (int m = 0; m < 4; ++m) a[m] = *(const bf16x8_t*)(b + m * 1024 + lofs);
  };
  auto ldB = [&](bf16x8_t (&bv)[4], int tile) {
    const __hip_bfloat16* p = gB + tile * 32;
    #pragma unroll
    for (int n = 0; n < 4; ++n) bv[n] = LD8(p + n * nstep);
  };

  f32x4_t acc[4][4] = {};
  auto mma = [&](bf16x8_t (&a)[4], bf16x8_t (&bv)[4]) {
    __builtin_amdgcn_s_setprio(1);
    #pragma unroll
    for (int m = 0; m < 4; ++m)
      #pragma unroll
      for (int n = 0; n < 4; ++n)
        acc[m][n] = __builtin_amdgcn_mfma_f32_16x16x32_bf16(a[m], bv[n], acc[m][n], 0, 0, 0);
    __builtin_amdgcn_s_setprio(0);
  };

  const int NT = K >> 5;   // NT even, >= 4
  bf16x8_t a0[4], b0[4], a1[4], b1[4];

  // prologue: LDS tiles 0,1; S-sets hold tiles 2(E),3(O)
  loadE(0); loadO(1); writeE(0); writeO(1); loadE(2); loadO(3);
  asm volatile("s_waitcnt lgkmcnt(0)" ::: "memory");
  __builtin_amdgcn_s_barrier();
  rdA(a0, 0); ldB(b0, 0);

  for (int kt = 0; kt < NT; kt += 2) {
    // even body: compute tile kt, prefetch kt+1, stage kt+2, load kt+4
    ldB(b1, kt + 1); rdA(a1, kt + 1);
    if (kt + 2 < NT) writeE(kt + 2);
    if (kt + 4 < NT) loadE(kt + 4);
    mma(a0, b0);
    asm volatile("s_waitcnt lgkmcnt(0)" ::: "memory");
    __builtin_amdgcn_s_barrier();
    // odd body: compute tile kt+1
    const int k2 = kt + 1;
    if (k2 + 1 < NT) { ldB(b0, k2 + 1); rdA(a0, k2 + 1); }
    if (k2 + 2 < NT) writeO(k2 + 2);
    if (k2 + 4 < NT) loadO(k2 + 4);
    mma(a1, b1);
    asm volatile("s_waitcnt lgkmcnt(0)" ::: "memory");
    __builtin_amdgcn_s_barrier();
  }

  // epilogue: C/D layout col=lane&15, row=(lane>>4)*4+j
  #pragma unroll
  for (int m = 0; m < 4; ++m) {
    #pragma unroll
    for (int n = 0; n < 4; ++n) {
      const int gcol = n0 + wc * 64 + n * 16 + rr;
      #pragma unroll
      for (int j = 0; j < 4; ++j) {
        const int grow = m0 + wr * 64 + m * 16 + kq * 4 + j;
        float v = acc[m][n][j] + bias[gcol];
        if (EP == 0) {
          if (gcol < 512) v *= 0.17677669529663687f;  // hd^-0.5
          obf[(size_t)grow * Ncols + gcol] = __float2bfloat16(v);
        } else if (EP == 1) {
          int bw = grow / 49, nn = grow - bw * 49;
          int b = bw >> 6, wi = bw & 63;
          int hh = (wi >> 3) * 7 + nn / 7 + 3;  if (hh >= 56) hh -= 56;
          int ww2 = (wi & 7) * 7 + (nn % 7) + 3; if (ww2 >= 56) ww2 -= 56;
          size_t tok = (size_t)b * 3136 + hh * 56 + ww2;
          ofp[tok * 512 + gcol] = resid[tok * 512 + gcol] + v;
        } else if (EP == 2) {
          float u = 0.5f * v * (1.f + erff(v * 0.70710678118f));
          obf[(size_t)grow * Ncols + gcol] = __float2bfloat16(u);
        } else {
          ofp[(size_t)grow * 512 + gcol] += v;
        }
      }
    }
  }
}

extern "C" void kernel_launch(void* const* d_in, const int* in_sizes, int n_in,
                              void* d_out, int out_size, void* d_ws, size_t ws_size,
                              hipStream_t stream) {
  const float* x      = (const float*)d_in[0];
  const int*   rpi    = (const int*)  d_in[1];
  const float* amask  = (const float*)d_in[2];
  const float* n1g    = (const float*)d_in[3];
  const float* n1b    = (const float*)d_in[4];
  const float* qkv_w  = (const float*)d_in[5];
  const float* qkv_b  = (const float*)d_in[6];
  const float* proj_w = (const float*)d_in[7];
  const float* proj_b = (const float*)d_in[8];
  const float* rpb_t  = (const float*)d_in[9];
  const float* n2g    = (const float*)d_in[10];
  const float* n2b    = (const float*)d_in[11];
  const float* w1     = (const float*)d_in[12];
  const float* b1     = (const float*)d_in[13];
  const float* w2     = (const float*)d_in[14];
  const float* b2     = (const float*)d_in[15];
  float* out = (float*)d_out;

  char* ws = (char*)d_ws;
  const size_t M = 50176;
  const size_t szA = M * 2048 * 2;          // region A: xw -> o -> m   (tail reused for cmbp)
  const size_t szB = M * 1536 * 2;          // region B: qkv -> h2
  const size_t offB = szA;
  const size_t offW = offB + szB;
  __hip_bfloat16* bufA = (__hip_bfloat16*)(ws);
  __hip_bfloat16* bufB = (__hip_bfloat16*)(ws + offB);
  __hip_bfloat16* wqkv  = (__hip_bfloat16*)(ws + offW);
  __hip_bfloat16* wproj = wqkv + 786432;
  __hip_bfloat16* wm1   = wproj + 262144;
  __hip_bfloat16* wm2   = wm1 + 1048576;
  float* cmbp = (float*)(ws + szA - (size_t)4194304 * 4);

  k_cvt<<<3072, 256, 0, stream>>>(qkv_w, wqkv, 786432);
  k_cvt<<<1024, 256, 0, stream>>>(proj_w, wproj, 262144);
  k_cvt<<<4096, 256, 0, stream>>>(w1, wm1, 1048576);
  k_cvt<<<4096, 256, 0, stream>>>(w2, wm2, 1048576);
  k_cmb<<<16384, 256, 0, stream>>>(rpi, rpb_t, amask, cmbp);

  // LN1 + shift + window partition -> bufA (bf16, [50176][512])
  k_ln<1><<<50176, 256, 0, stream>>>(x, n1g, n1b, bufA);
  // QKV: bufA @ wqkv^T -> bufB (bf16, [50176][1536], q pre-scaled)
  gemm_bd<0><<<196 * 12, 512, 0, stream>>>(bufA, wqkv, 512, 1536, 12, qkv_b, bufB, nullptr, nullptr);
  // MFMA attention -> bufA (bf16, [50176][512])
  k_attn<<<dim3(1024, 4), 256, 0, stream>>>(bufB, cmbp, bufA);
  // proj + window reverse + unshift + residual -> d_out (f32)
  gemm_bd<1><<<196 * 4, 512, 0, stream>>>(bufA, wproj, 512, 512, 4, proj_b, nullptr, x, out);
  // LN2 -> bufB (bf16, [50176][512])
  k_ln<0><<<50176, 256, 0, stream>>>(out, n2g, n2b, bufB);
  // MLP1 + GELU -> bufA (bf16, [50176][2048])
  gemm_bd<2><<<196 * 16, 512, 0, stream>>>(bufB, wm1, 512, 2048, 16, b1, bufA, nullptr, nullptr);
  // MLP2 + residual accumulate -> d_out
  gemm_bd<3><<<196 * 4, 512, 0, stream>>>(bufA, wm2, 2048, 512, 4, b2, nullptr, nullptr, out);
}

// Round 9
// 808.046 us; speedup vs baseline: 1.5481x; 1.5481x over previous
//
#include <hip/hip_runtime.h>
#include <hip/hip_bf16.h>

typedef __attribute__((ext_vector_type(8))) short bf16x8_t;
typedef __attribute__((ext_vector_type(4))) float f32x4_t;

#define LD8(p) (*(const bf16x8_t*)(p))

__device__ __forceinline__ void gll16(const void* g, void* l) {
  __builtin_amdgcn_global_load_lds((const __attribute__((address_space(1))) void*)g,
                                   (__attribute__((address_space(3))) void*)l, 16, 0, 0);
}

// ---------------- f32 -> bf16 convert ----------------
__global__ __launch_bounds__(256) void k_cvt(const float* __restrict__ in,
                                             __hip_bfloat16* __restrict__ out, int n) {
  int i = blockIdx.x * 256 + threadIdx.x;
  if (i < n) out[i] = __float2bfloat16(in[i]);
}

// ---------------- cmbp: rpb+mask packed in MFMA C-fragment order ----------------
__global__ __launch_bounds__(256) void k_cmb(const int* __restrict__ rpi,
                                             const float* __restrict__ tab,
                                             const float* __restrict__ mask,
                                             float* __restrict__ cmbp) {
  int idx = blockIdx.x * 256 + threadIdx.x;   // < 64*16*16*256 = 4194304
  int jj = idx & 3, lane = (idx >> 2) & 63, tile = (idx >> 8) & 15;
  int h = (idx >> 12) & 15, w6 = idx >> 16;
  int r = (tile >> 2) * 16 + (lane >> 4) * 4 + jj;
  int c = (tile & 3) * 16 + (lane & 15);
  float v = -1e9f;
  if (r < 49 && c < 49) v = tab[rpi[r * 49 + c] * 16 + h] + mask[w6 * 2401 + r * 49 + c];
  cmbp[idx] = v;
}

// ---------------- layernorm (+optional shift+window-partition), f32 -> bf16 ----------------
template<int PERM>
__global__ __launch_bounds__(256) void k_ln(const float* __restrict__ in,
                                            const float* __restrict__ g,
                                            const float* __restrict__ bta,
                                            __hip_bfloat16* __restrict__ out) {
  int token = blockIdx.x;
  int t = threadIdx.x;
  const float2 v = ((const float2*)(in + (size_t)token * 512))[t];
  float s = v.x + v.y, sq = v.x * v.x + v.y * v.y;
  #pragma unroll
  for (int d = 1; d < 64; d <<= 1) { s += __shfl_xor(s, d); sq += __shfl_xor(sq, d); }
  __shared__ float ps[4], pq[4];
  int w = t >> 6;
  if ((t & 63) == 0) { ps[w] = s; pq[w] = sq; }
  __syncthreads();
  s  = ps[0] + ps[1] + ps[2] + ps[3];
  sq = pq[0] + pq[1] + pq[2] + pq[3];
  float mean = s * (1.f / 512.f);
  float inv = rsqrtf(sq * (1.f / 512.f) - mean * mean + 1e-5f);
  size_t dst;
  if (PERM) {
    int b = token / 3136, p = token - b * 3136;
    int i = p / 56, j = p - i * 56;
    int gi = (i + 53) % 56, gj = (j + 53) % 56;       // (i-3) mod 56
    dst = ((size_t)(((b * 64) + (gi / 7) * 8 + (gj / 7)) * 49) + (gi % 7) * 7 + (gj % 7)) * 512;
  } else {
    dst = (size_t)token * 512;
  }
  int c = t * 2;
  out[dst + c]     = __float2bfloat16((v.x - mean) * inv * g[c] + bta[c]);
  out[dst + c + 1] = __float2bfloat16((v.y - mean) * inv * g[c + 1] + bta[c + 1]);
}

// ---------------- MFMA windowed attention: one wave per (window, head) ----------------
__global__ __launch_bounds__(256) void k_attn(const __hip_bfloat16* __restrict__ qkv,
                                              const float* __restrict__ cmbp,
                                              __hip_bfloat16* __restrict__ o) {
  __shared__ __align__(16) __hip_bfloat16 vt_all[4 * 32 * 72];
  __shared__ __align__(16) __hip_bfloat16 P_all[4 * 64 * 72];
  const int t = threadIdx.x, l = t & 63, w = t >> 6;
  const int bw = blockIdx.x;
  const int head = blockIdx.y * 4 + w;
  const int rr = l & 15, g = l >> 4;
  __hip_bfloat16* vt = vt_all + w * (32 * 72);
  __hip_bfloat16* P  = P_all  + w * (64 * 72);
  const __hip_bfloat16* base = qkv + (size_t)bw * 49 * 1536 + head * 32;
  const bf16x8_t zero8 = {};

  { int d = l >> 1, sg = (l & 1) * 8;
    *(bf16x8_t*)(vt + d * 72 + 48 + sg) = zero8; }
  __builtin_amdgcn_sched_barrier(0);
  #pragma unroll
  for (int it = 0; it < 4; ++it) {
    int idx = l + it * 64;
    if (idx < 196) {
      int j = idx >> 2, sg = (idx & 3) * 8;
      bf16x8_t vv = *(const bf16x8_t*)(base + 1024 + (size_t)j * 1536 + sg);
      #pragma unroll
      for (int s2 = 0; s2 < 8; ++s2) vt[(sg + s2) * 72 + j] = ((__hip_bfloat16*)&vv)[s2];
    }
  }
  bf16x8_t aq[4], bk[4];
  #pragma unroll
  for (int m = 0; m < 4; ++m) {
    int row = m * 16 + rr;
    aq[m] = (row < 49) ? *(const bf16x8_t*)(base + (size_t)row * 1536 + g * 8) : zero8;
    bk[m] = (row < 49) ? *(const bf16x8_t*)(base + 512 + (size_t)row * 1536 + g * 8) : zero8;
  }
  const float4* cp = (const float4*)(cmbp + (size_t)((bw & 63) * 16 + head) * 4096);
  f32x4_t S[4][4];
  #pragma unroll
  for (int tm = 0; tm < 4; ++tm)
    #pragma unroll
    for (int tn = 0; tn < 4; ++tn) {
      float4 cv = cp[(tm * 4 + tn) * 64 + l];
      f32x4_t c0 = { cv.x, cv.y, cv.z, cv.w };
      S[tm][tn] = __builtin_amdgcn_mfma_f32_16x16x32_bf16(aq[tm], bk[tn], c0, 0, 0, 0);
    }
  float sm[4][4];
  #pragma unroll
  for (int tm = 0; tm < 4; ++tm) {
    #pragma unroll
    for (int jj = 0; jj < 4; ++jj) {
      float v = fmaxf(fmaxf(S[tm][0][jj], S[tm][1][jj]), fmaxf(S[tm][2][jj], S[tm][3][jj]));
      v = fmaxf(v, __shfl_xor(v, 1));
      v = fmaxf(v, __shfl_xor(v, 2));
      v = fmaxf(v, __shfl_xor(v, 4));
      v = fmaxf(v, __shfl_xor(v, 8));
      float s = 0.f;
      #pragma unroll
      for (int tn = 0; tn < 4; ++tn) {
        float e = __expf(S[tm][tn][jj] - v);
        S[tm][tn][jj] = e;
        s += e;
      }
      s += __shfl_xor(s, 1); s += __shfl_xor(s, 2); s += __shfl_xor(s, 4); s += __shfl_xor(s, 8);
      sm[tm][jj] = s;
    }
  }
  #pragma unroll
  for (int tm = 0; tm < 4; ++tm)
    #pragma unroll
    for (int tn = 0; tn < 4; ++tn)
      #pragma unroll
      for (int jj = 0; jj < 4; ++jj)
        P[(tm * 16 + g * 4 + jj) * 72 + tn * 16 + rr] = __float2bfloat16(S[tm][tn][jj]);

  f32x4_t O[4][2] = {};
  #pragma unroll
  for (int ks = 0; ks < 2; ++ks) {
    bf16x8_t pa[4], vb[2];
    #pragma unroll
    for (int tm = 0; tm < 4; ++tm)
      pa[tm] = *(const bf16x8_t*)(P + (tm * 16 + rr) * 72 + ks * 32 + g * 8);
    #pragma unroll
    for (int tn = 0; tn < 2; ++tn)
      vb[tn] = *(const bf16x8_t*)(vt + (tn * 16 + rr) * 72 + ks * 32 + g * 8);
    #pragma unroll
    for (int tm = 0; tm < 4; ++tm)
      #pragma unroll
      for (int tn = 0; tn < 2; ++tn)
        O[tm][tn] = __builtin_amdgcn_mfma_f32_16x16x32_bf16(pa[tm], vb[tn], O[tm][tn], 0, 0, 0);
  }
  #pragma unroll
  for (int tm = 0; tm < 4; ++tm) {
    #pragma unroll
    for (int jj = 0; jj < 4; ++jj) {
      int r = tm * 16 + g * 4 + jj;
      if (r < 49) {
        float rcp = 1.f / sm[tm][jj];
        size_t ob = ((size_t)bw * 49 + r) * 512 + head * 32;
        o[ob + rr]      = __float2bfloat16(O[tm][0][jj] * rcp);
        o[ob + 16 + rr] = __float2bfloat16(O[tm][1][jj] * rcp);
      }
    }
  }
}

// ---------------- 256x256 bf16 GEMM: BK=64 quadrant-phase pipeline, counted vmcnt(4) ----------------
// dbuf-2 (tile t -> buf t&1). Per K-tile, 4 quadrant phases; staggered half-tile staging:
//   ph1: read Alo+Blo, stage Ahi(t+1); ph2: read Ahi, stage Bhi(t+1); [mid barrier]
//   ph3: read Bhi, stage Alo(t+2); ph4: (reg reuse), stage Blo(t+2); vmcnt(4); [barrier]
// Steady state: entering tile t, 4 gll16 outstanding (lo-halves of t+1); vmcnt(4) proves all of
// t+1 landed while keeping t+2's lo-halves in flight (never drains to 0). 2 barriers/K-tile.
template<int EP>
__global__ __launch_bounds__(512, 2) void gemm256(const __hip_bfloat16* __restrict__ A,
                                                  const __hip_bfloat16* __restrict__ Bw,
                                                  int K, int Ncols, int nNB,
                                                  const float* __restrict__ bias,
                                                  __hip_bfloat16* __restrict__ obf,
                                                  const float* __restrict__ resid,
                                                  float* __restrict__ ofp) {
  __shared__ __align__(16) char LDS[131072];  // A: [2buf][2half][16KB] at 0; B same at 65536
  const int nwg = gridDim.x, orig = blockIdx.x;
  const int q8 = nwg >> 3, r8 = nwg & 7;
  const int xcd = orig & 7, lin = orig >> 3;
  const int wgid = (xcd < r8 ? xcd * (q8 + 1) : r8 * (q8 + 1) + (xcd - r8) * q8) + lin;
  const int bx = wgid / nNB, by = wgid - bx * nNB;
  const int m0 = bx * 256, n0 = by * 256;
  const int t = threadIdx.x, l = t & 63, w = t >> 6;
  const int wr = w >> 2, wc = w & 3;                 // wave: m-half wr, n-quarter wc
  const int rr = l & 15, kq = l >> 4;
  const int swzo = (kq * 16) ^ ((rr & 8) << 2);      // swizzled byte-in-row for frag reads

  // staging decode: thread covers LDS bytes d0=t*16 (ks=0 region) and d1=8192+t*16 (ks=1)
  int rs0, cs0, rs1, cs1;
  { int d = t * 16;  rs0 = (d >> 10) * 16 + ((d >> 6) & 15);
    cs0 = ((d & 63) ^ (((d >> 9) & 1) << 5)) >> 1; }
  { int d = 8192 + t * 16; int dd = d & 8191;
    rs1 = (dd >> 10) * 16 + ((dd >> 6) & 15);
    cs1 = 32 + (((d & 63) ^ (((d >> 9) & 1) << 5)) >> 1); }
  const __hip_bfloat16* gA = A + (size_t)m0 * K;
  const __hip_bfloat16* gB = Bw + (size_t)n0 * K;

  // stage half h of tile T (A if base 0, B if base 65536): 2 gll16, linear dest = swizzled layout
  auto stageA = [&](int T, int h) {
    char* dst = LDS + (T & 1) * 32768 + h * 16384 + t * 16;
    const size_t kb = (size_t)T * 64;
    gll16(gA + (size_t)(h * 128 + rs0) * K + kb + cs0, dst);
    gll16(gA + (size_t)(h * 128 + rs1) * K + kb + cs1, dst + 8192);
  };
  auto stageB = [&](int T, int h) {
    char* dst = LDS + 65536 + (T & 1) * 32768 + h * 16384 + t * 16;
    const size_t kb = (size_t)T * 64;
    gll16(gB + (size_t)(h * 128 + rs0) * K + kb + cs0, dst);
    gll16(gB + (size_t)(h * 128 + rs1) * K + kb + cs1, dst + 8192);
  };

  // fragment reads (wave-local halves)
  auto ldA = [&](bf16x8_t (&a)[4][2], int buf, int mq) {
    const char* b = LDS + buf * 32768 + wr * 16384;
    #pragma unroll
    for (int m = 0; m < 4; ++m)
      #pragma unroll
      for (int ks = 0; ks < 2; ++ks)
        a[m][ks] = *(const bf16x8_t*)(b + ks * 8192 + (mq * 4 + m) * 1024 + rr * 64 + swzo);
  };
  auto ldB = [&](bf16x8_t (&bv)[2][2], int buf, int nq) {
    const char* b = LDS + 65536 + buf * 32768 + (wc >> 1) * 16384;
    #pragma unroll
    for (int n = 0; n < 2; ++n)
      #pragma unroll
      for (int ks = 0; ks < 2; ++ks)
        bv[n][ks] = *(const bf16x8_t*)(b + ks * 8192 + ((wc & 1) * 4 + nq * 2 + n) * 1024 + rr * 64 + swzo);
  };

  f32x4_t acc[8][4] = {};
  auto mma = [&](bf16x8_t (&a)[4][2], bf16x8_t (&bv)[2][2], int mq, int nq) {
    __builtin_amdgcn_s_setprio(1);
    #pragma unroll
    for (int m = 0; m < 4; ++m)
      #pragma unroll
      for (int n = 0; n < 2; ++n)
        #pragma unroll
        for (int ks = 0; ks < 2; ++ks)
          acc[mq * 4 + m][nq * 2 + n] =
            __builtin_amdgcn_mfma_f32_16x16x32_bf16(a[m][ks], bv[n][ks], acc[mq * 4 + m][nq * 2 + n], 0, 0, 0);
    __builtin_amdgcn_s_setprio(0);
  };

  const int NT = K >> 6;   // K multiple of 64, NT >= 2
  // prologue: tile 0 all 4 halves, tile 1 lo-halves; vmcnt(4) -> tile 0 landed
  stageA(0, 0); stageB(0, 0); stageA(0, 1); stageB(0, 1);
  if (1 < NT) { stageA(1, 0); stageB(1, 0); }
  if (1 < NT) asm volatile("s_waitcnt vmcnt(4)" ::: "memory");
  else        asm volatile("s_waitcnt vmcnt(0)" ::: "memory");
  __builtin_amdgcn_s_barrier();

  for (int kt = 0; kt < NT; ++kt) {
    const int cur = kt & 1;
    bf16x8_t Alo[4][2], Ahi[4][2], B0[2][2], B1[2][2];
    // ph1: quad (m-lo, n-lo)
    ldA(Alo, cur, 0); ldB(B0, cur, 0);
    if (kt + 1 < NT) stageA(kt + 1, 1);
    asm volatile("s_waitcnt lgkmcnt(0)" ::: "memory");
    __builtin_amdgcn_sched_barrier(0);
    mma(Alo, B0, 0, 0);
    // ph2: quad (m-hi, n-lo)
    ldA(Ahi, cur, 1);
    if (kt + 1 < NT) stageB(kt + 1, 1);
    asm volatile("s_waitcnt lgkmcnt(0)" ::: "memory");
    __builtin_amdgcn_sched_barrier(0);
    mma(Ahi, B0, 1, 0);
    __builtin_amdgcn_s_barrier();          // mid: lo-regions of buf[cur] now reusable
    // ph3: quad (m-hi, n-hi)
    ldB(B1, cur, 1);
    if (kt + 2 < NT) stageA(kt + 2, 0);
    asm volatile("s_waitcnt lgkmcnt(0)" ::: "memory");
    __builtin_amdgcn_sched_barrier(0);
    mma(Ahi, B1, 1, 1);
    // ph4: quad (m-lo, n-hi) — register reuse, no LDS reads
    if (kt + 2 < NT) stageB(kt + 2, 0);
    mma(Alo, B1, 0, 1);
    // checkpoint: everything for tile kt+1 must have landed; keep kt+2's lo-halves in flight
    if (kt + 1 < NT) {
      if (kt + 2 < NT) asm volatile("s_waitcnt vmcnt(4)" ::: "memory");
      else             asm volatile("s_waitcnt vmcnt(0)" ::: "memory");
    }
    __builtin_amdgcn_s_barrier();
  }

  // epilogue: C/D layout col=lane&15, row=(lane>>4)*4+j
  #pragma unroll
  for (int m = 0; m < 8; ++m) {
    #pragma unroll
    for (int n = 0; n < 4; ++n) {
      const int gcol = n0 + wc * 64 + n * 16 + rr;
      #pragma unroll
      for (int j = 0; j < 4; ++j) {
        const int grow = m0 + wr * 128 + m * 16 + kq * 4 + j;
        float v = acc[m][n][j] + bias[gcol];
        if (EP == 0) {
          if (gcol < 512) v *= 0.17677669529663687f;  // hd^-0.5
          obf[(size_t)grow * Ncols + gcol] = __float2bfloat16(v);
        } else if (EP == 1) {
          int bw = grow / 49, nn = grow - bw * 49;
          int b = bw >> 6, wi = bw & 63;
          int hh = (wi >> 3) * 7 + nn / 7 + 3;  if (hh >= 56) hh -= 56;
          int ww2 = (wi & 7) * 7 + (nn % 7) + 3; if (ww2 >= 56) ww2 -= 56;
          size_t tok = (size_t)b * 3136 + hh * 56 + ww2;
          ofp[tok * 512 + gcol] = resid[tok * 512 + gcol] + v;
        } else if (EP == 2) {
          float u = 0.5f * v * (1.f + erff(v * 0.70710678118f));
          obf[(size_t)grow * Ncols + gcol] = __float2bfloat16(u);
        } else {
          ofp[(size_t)grow * 512 + gcol] += v;
        }
      }
    }
  }
}

extern "C" void kernel_launch(void* const* d_in, const int* in_sizes, int n_in,
                              void* d_out, int out_size, void* d_ws, size_t ws_size,
                              hipStream_t stream) {
  const float* x      = (const float*)d_in[0];
  const int*   rpi    = (const int*)  d_in[1];
  const float* amask  = (const float*)d_in[2];
  const float* n1g    = (const float*)d_in[3];
  const float* n1b    = (const float*)d_in[4];
  const float* qkv_w  = (const float*)d_in[5];
  const float* qkv_b  = (const float*)d_in[6];
  const float* proj_w = (const float*)d_in[7];
  const float* proj_b = (const float*)d_in[8];
  const float* rpb_t  = (const float*)d_in[9];
  const float* n2g    = (const float*)d_in[10];
  const float* n2b    = (const float*)d_in[11];
  const float* w1     = (const float*)d_in[12];
  const float* b1     = (const float*)d_in[13];
  const float* w2     = (const float*)d_in[14];
  const float* b2     = (const float*)d_in[15];
  float* out = (float*)d_out;

  char* ws = (char*)d_ws;
  const size_t M = 50176;
  const size_t szA = M * 2048 * 2;          // region A: xw -> o -> m   (tail reused for cmbp)
  const size_t szB = M * 1536 * 2;          // region B: qkv -> h2
  const size_t offB = szA;
  const size_t offW = offB + szB;
  __hip_bfloat16* bufA = (__hip_bfloat16*)(ws);
  __hip_bfloat16* bufB = (__hip_bfloat16*)(ws + offB);
  __hip_bfloat16* wqkv  = (__hip_bfloat16*)(ws + offW);
  __hip_bfloat16* wproj = wqkv + 786432;
  __hip_bfloat16* wm1   = wproj + 262144;
  __hip_bfloat16* wm2   = wm1 + 1048576;
  float* cmbp = (float*)(ws + szA - (size_t)4194304 * 4);

  k_cvt<<<3072, 256, 0, stream>>>(qkv_w, wqkv, 786432);
  k_cvt<<<1024, 256, 0, stream>>>(proj_w, wproj, 262144);
  k_cvt<<<4096, 256, 0, stream>>>(w1, wm1, 1048576);
  k_cvt<<<4096, 256, 0, stream>>>(w2, wm2, 1048576);
  k_cmb<<<16384, 256, 0, stream>>>(rpi, rpb_t, amask, cmbp);

  // LN1 + shift + window partition -> bufA (bf16, [50176][512])
  k_ln<1><<<50176, 256, 0, stream>>>(x, n1g, n1b, bufA);
  // QKV: bufA @ wqkv^T -> bufB (bf16, [50176][1536], q pre-scaled)
  gemm256<0><<<196 * 6, 512, 0, stream>>>(bufA, wqkv, 512, 1536, 6, qkv_b, bufB, nullptr, nullptr);
  // MFMA attention -> bufA (bf16, [50176][512])
  k_attn<<<dim3(1024, 4), 256, 0, stream>>>(bufB, cmbp, bufA);
  // proj + window reverse + unshift + residual -> d_out (f32)
  gemm256<1><<<196 * 2, 512, 0, stream>>>(bufA, wproj, 512, 512, 2, proj_b, nullptr, x, out);
  // LN2 -> bufB (bf16, [50176][512])
  k_ln<0><<<50176, 256, 0, stream>>>(out, n2g, n2b, bufB);
  // MLP1 + GELU -> bufA (bf16, [50176][2048])
  gemm256<2><<<196 * 8, 512, 0, stream>>>(bufB, wm1, 512, 2048, 8, b1, bufA, nullptr, nullptr);
  // MLP2 + residual accumulate -> d_out
  gemm256<3><<<196 * 2, 512, 0, stream>>>(bufA, wm2, 2048, 512, 2, b2, nullptr, nullptr, out);
}